// Round 15
// baseline (104.127 us; speedup 1.0000x reference)
//
#include <hip/hip_runtime.h>

#define NPRED 1445
#define RAWSTR 1472    // padded per-image stride for raw arrays
#define NCLS  80
#define MAXDET 300
#define OUTC  86
#define CONF_T 0.6f
#define IOU_T  0.45f
#define MAX_WH 4096.0f
#define HWSZ  289
#define NIMG  32
#define SLOTS 768      // compacted slots per image (M mean ~396, sigma ~17)
#define MCAP  512      // edge fast-path cap (~7 sigma)
#define EPB   256      // edge capacity per (image, j-word) region
#define EWALK 2048     // 8*EPB: max edges the walk path handles

// ---- d_ws layout (bytes); footprint identical to round-14 proven layout ----
#define OFF_CNT  128        // (unused; layout stability)
#define OFF_KEYR 256        // u64[32][RAWSTR]  raw keys by candidate (sentinel ~0)
#define OFF_BOXR 377088     // float4[32][RAWSTR] raw offset boxes by candidate
#define OFF_KEY  1130752    // u64[32][SLOTS]   rank-sorted keys
#define OFF_DONE 1327360    // int[32] per-image completion counters (was wsSBox)
#define OFF_ECNT 1720576    // int[32][8]       per-region edge counts
#define OFF_EDG  1721600    // u32[32][8][EPB]  edges (i<<9|j), unsorted
#define OFF_DST  1983744    // int[32][MAXDET]  RANK per kept output row
#define WS_NEED  2022144
// wsKept = int[32] at offset 0

__device__ __forceinline__ unsigned long long bcast64(unsigned long long v, int srcLane) {
    unsigned lo = (unsigned)__builtin_amdgcn_readlane((int)(unsigned)(v & 0xFFFFFFFFULL), srcLane);
    unsigned hi = (unsigned)__builtin_amdgcn_readlane((int)(unsigned)(v >> 32), srcLane);
    return ((unsigned long long)hi << 32) | lo;
}

// ================= kernel 1: per-candidate prep (deterministic slots, no atomics) =====
__global__ __launch_bounds__(128)
void prep_kernel(const float* __restrict__ score, unsigned long long* __restrict__ wsKeyRaw,
                 float4* __restrict__ wsBoxRaw, int* __restrict__ wsDone) {
    const int b = blockIdx.x;
    if (blockIdx.y == 0 && threadIdx.x == 0) wsDone[b] = 0;   // reset signal each call
    const int ci = blockIdx.y * 128 + threadIdx.x;
    if (ci >= NPRED) return;
    const int t5 = ci / HWSZ;
    const int hw = ci - t5 * HWSZ;
    const int n = hw * 5 + t5;                     // candidate row in x[N][85]
    const float* base = score + (size_t)b * 425 * HWSZ + (size_t)(t5 * 85) * HWSZ + hw;
    float x = base[0];
    float y = base[HWSZ];
    float w = base[2 * HWSZ];
    float h = base[3 * HWSZ];
    float obj = base[4 * HWSZ];

    float best = -INFINITY; int bj = 0;
    #pragma unroll 16
    for (int k = 0; k < NCLS; ++k) {
        float v = base[(5 + k) * HWSZ] * obj;      // cls = logits * obj
        if (v > best) { best = v; bj = k; }        // strict >: first-occurrence argmax
    }

    float wh2 = w * 0.5f, hh2 = h * 0.5f;
    float x1 = x - wh2, y1 = y - hh2, x2 = x + wh2, y2 = y + hh2;
    float off = (float)bj * MAX_WH;                // exact product

    unsigned long long key = ~0ULL;                // invalid sentinel (MSB set)
    if ((obj > CONF_T) && (best > CONF_T)) {
        unsigned int u = __float_as_uint(best);    // conf > 0.6 -> positive, MSB 0
        unsigned int desc = ~(u | 0x80000000u);    // ascending u64 == descending conf
        key = ((unsigned long long)desc << 32)
            | ((unsigned long long)(unsigned)n << 16)
            | ((unsigned long long)(unsigned)bj << 8);
    }
    wsKeyRaw[b * RAWSTR + ci] = key;
    wsBoxRaw[b * RAWSTR + ci] = make_float4(x1 + off, y1 + off, x2 + off, y2 + off);
}

// ================= kernel 2: compact+sort + edges; LAST block per image also scans ====
// grid (NIMG, 8): block (b,w) sorts locally (identical across blocks), extracts edges
// for j-word w (triangular i-limit), signals wsDone[b]; the 8th signaler runs the
// proven edge-walk NMS in-place (it already holds sorted boxes in LDS).
struct EdgeSh {
    float sx1[SLOTS], sy1[SLOTS], sx2[SLOTS], sy2[SLOTS];   // 12288 B
    union {
        struct { unsigned long long keys[NPRED]; unsigned long long cke[SLOTS]; } a; // 17704 B
        struct { unsigned int eraw[EWALK]; unsigned int esrt[EWALK]; } e;            // 16384 B
        unsigned char kp[SLOTS];                                                     // fallback
    } u;
    unsigned short cidx[SLOTS];                              //  1536 B
    int wtot[16];
    int mTot, ecnt, lastFlag, over;
    int ec[8];
    int eoff[9];
};

__global__ __launch_bounds__(1024)
void edge_scan_kernel(const unsigned long long* __restrict__ wsKeyRaw,
                      const float4* __restrict__ wsBoxRaw,
                      unsigned long long* __restrict__ wsKey,
                      int* __restrict__ wsECnt, unsigned int* __restrict__ wsEdges,
                      int* __restrict__ wsDone,
                      int* __restrict__ wsKept, int* __restrict__ wsDst) {
    __shared__ EdgeSh s;
    const int b = blockIdx.x, w = blockIdx.y, tid = threadIdx.x;
    const int lane = tid & 63, wid = tid >> 6;

    for (int i = tid; i < NPRED; i += 1024) s.u.a.keys[i] = wsKeyRaw[b * RAWSTR + i];
    if (tid == 0) s.ecnt = 0;
    __syncthreads();

    // ---- validity prefix-sum compaction (proven round-12/14 logic) ----
    const int i0 = tid, i1 = tid + 1024;
    const bool v0 = (s.u.a.keys[i0] >> 63) == 0ULL;           // valid keys have MSB 0
    const bool v1 = (i1 < NPRED) && ((s.u.a.keys[i1] >> 63) == 0ULL);
    int cnt = (int)v0 + (int)v1;
    int inc = cnt;
    #pragma unroll
    for (int m = 1; m < 64; m <<= 1) {
        int v = __shfl_up(inc, m, 64);
        if (lane >= m) inc += v;
    }
    if (lane == 63) s.wtot[wid] = inc;
    __syncthreads();
    int basep = 0;
    for (int w2 = 0; w2 < wid; ++w2) basep += s.wtot[w2];
    int pos = basep + inc - cnt;                              // exclusive global prefix
    if (v0 && pos < SLOTS) s.cidx[pos] = (unsigned short)i0;
    if (v1 && pos + (int)v0 < SLOTS) s.cidx[pos + (int)v0] = (unsigned short)i1;
    if (tid == 0) {
        int t = 0;
        for (int w2 = 0; w2 < 16; ++w2) t += s.wtot[w2];
        s.mTot = t;
    }
    __syncthreads();
    int M = s.mTot; if (M > SLOTS) M = SLOTS;
    if (tid < M) s.u.a.cke[tid] = s.u.a.keys[s.cidx[tid]];    // densify (M <= 768)
    __syncthreads();

    // ---- rank-count sort (identical in every block; unique keys) ----
    if (tid < M) {
        unsigned long long ki = s.u.a.cke[tid];
        int rank = 0;
        #pragma unroll 4
        for (int j2 = 0; j2 < M; ++j2) rank += (s.u.a.cke[j2] < ki) ? 1 : 0;
        float4 bx = wsBoxRaw[b * RAWSTR + s.cidx[tid]];
        s.sx1[rank] = bx.x; s.sy1[rank] = bx.y; s.sx2[rank] = bx.z; s.sy2[rank] = bx.w;
        if (w == 0) wsKey[b * SLOTS + rank] = ki;             // persist once per image
    }
    __syncthreads();                                          // u.a dead below

    // ---- edge extraction for j-word w, triangular i-limit ----
    if (M <= MCAP) {
        unsigned int* reg = wsEdges + (size_t)(b * 8 + w) * EPB;
        const int j = (w << 6) + lane;
        float jx1 = 0.f, jy1 = 0.f, jx2 = 0.f, jy2 = 0.f, ab = 0.f;
        const bool jok = (j < M);
        if (jok) {
            jx1 = s.sx1[j]; jy1 = s.sy1[j]; jx2 = s.sx2[j]; jy2 = s.sy2[j];
            ab = (jx2 - jx1) * (jy2 - jy1);
        }
        int ilim = (w + 1) << 6; if (ilim > M) ilim = M;      // only i < max j matter
        for (int i = wid; i < ilim; i += 16) {
            float ax1 = s.sx1[i], ay1 = s.sy1[i], ax2 = s.sx2[i], ay2 = s.sy2[i];
            float aa = (ax2 - ax1) * (ay2 - ay1);
            bool sup = false;
            if (jok && j > i) {
                float ltx = fmaxf(ax1, jx1), lty = fmaxf(ay1, jy1);
                float rbx = fminf(ax2, jx2), rby = fminf(ay2, jy2);
                float ww = fmaxf(rbx - ltx, 0.0f), hh = fmaxf(rby - lty, 0.0f);
                float inter = ww * hh;
                float denom = ((aa + ab) - inter) + 1e-9f;    // left-to-right, exact div
                sup = (inter / denom) > IOU_T;
            }
            unsigned long long mask = __ballot(sup);
            if (lane == 0 && mask) {
                int pc = __popcll(mask);
                int eb = atomicAdd(&s.ecnt, pc);              // LDS atomic, block-local
                int k = 0;
                while (mask) {
                    int bit = __ffsll((long long)mask) - 1;
                    mask &= mask - 1;
                    int p = eb + k;
                    if (p < EPB) reg[p] = ((unsigned)i << 9) | (unsigned)((w << 6) + bit);
                    ++k;
                }
            }
        }
    }

    // ---- signal completion (device-scope release), detect last block ----
    __threadfence();                                          // flush this thread's writes
    __syncthreads();
    if (tid == 0) {
        wsECnt[b * 8 + w] = (M <= MCAP) ? s.ecnt : 0x7FFFFFFF;
        __threadfence();                                      // flush count before signal
        int old = atomicAdd(&wsDone[b], 1);                   // device-scope atomic
        s.lastFlag = (old == 7) ? 1 : 0;
    }
    __syncthreads();
    if (!s.lastFlag) return;
    __threadfence();                                          // acquire peers' data

    // =================== scan phase: last block per image only ===================
    if (tid < 8) s.ec[tid] = wsECnt[b * 8 + tid];
    __syncthreads();
    if (tid == 0) {
        int o = 0, ov = 0;
        for (int w2 = 0; w2 < 8; ++w2) {
            s.eoff[w2] = o;
            int c = s.ec[w2];
            if (c > EPB) { ov = 1; c = (c == 0x7FFFFFFF) ? 0 : EPB; }
            o += c;
        }
        s.eoff[8] = o;
        s.over = ov;
    }
    __syncthreads();
    const bool fast = (M <= MCAP) && (s.over == 0);
    const int Etot = s.eoff[8];

    if (fast) {
        // ---- gather edges from 8 regions into LDS ----
        for (int w2 = 0; w2 < 8; ++w2) {
            int c = s.ec[w2]; if (c > EPB) c = EPB;
            const unsigned int* reg2 = wsEdges + (size_t)(b * 8 + w2) * EPB;
            for (int e2 = tid; e2 < c; e2 += 1024) s.u.e.eraw[s.eoff[w2] + e2] = reg2[e2];
        }
        __syncthreads();
        // ---- rank-count sort (unique (i<<9|j) values; E tiny) ----
        for (int e2 = tid; e2 < Etot; e2 += 1024) {
            unsigned int ke = s.u.e.eraw[e2];
            int rank = 0;
            for (int j2 = 0; j2 < Etot; ++j2) rank += (s.u.e.eraw[j2] < ke) ? 1 : 0;
            s.u.e.esrt[rank] = ke;
        }
        __syncthreads();
        if (tid < 64) {
            // ---- edge walk: lane l owns keep word l (proven structure) ----
            unsigned long long Kw = 0ULL;
            { int rem = M - (lane << 6);
              if (rem >= 64) Kw = ~0ULL; else if (rem > 0) Kw = (~0ULL) >> (64 - rem); }
            unsigned int A[8], B[8];
#define LOADE(buf, bs) { _Pragma("unroll") for (int k = 0; k < 8; ++k) { \
            int e2 = (bs) + k; buf[k] = (e2 < Etot) ? s.u.e.esrt[e2] : 0xFFFFFFFFu; } }
#define PROCE(buf) { _Pragma("unroll") for (int k = 0; k < 8; ++k) { \
            unsigned int ek = buf[k]; \
            if (ek != 0xFFFFFFFFu) { \
                int ei = (int)(ek >> 9), ej = (int)(ek & 511u); \
                unsigned long long kwi = bcast64(Kw, ei >> 6); \
                if ((kwi >> (ei & 63)) & 1ULL) { \
                    if (lane == (ej >> 6)) Kw &= ~(1ULL << (ej & 63)); \
                } } } }
            LOADE(A, 0)
            for (int e = 0; e < Etot; e += 16) {
                LOADE(B, e + 8)
                PROCE(A)
                LOADE(A, e + 16)
                PROCE(B)
            }
#undef LOADE
#undef PROCE
            // ---- compaction: lane-parallel popcount prefix ----
            int myc = __popcll(Kw);
            int incc = myc;
            #pragma unroll
            for (int m = 1; m < 64; m <<= 1) {
                int v = __shfl_up(incc, m, 64);
                if (lane >= m) incc += v;
            }
            int tot = __shfl(incc, 63, 64);
            if (lane == 0) wsKept[b] = (tot < MAXDET) ? tot : MAXDET;
            int r = incc - myc;                               // exclusive prefix
            unsigned long long kw = Kw;
            while (kw) {
                int i = __ffsll((long long)kw) - 1;
                kw &= kw - 1;
                if (r < MAXDET) wsDst[b * MAXDET + r] = (lane << 6) + i;  // RANK
                ++r;
            }
        }
    } else {
        // ---- fallback (M > MCAP or overflow, ~0 prob): barrier-serial greedy ----
        for (int r = tid; r < M; r += 1024) s.u.kp[r] = 1;
        __syncthreads();
        for (int i = 0; i < M; ++i) {
            if (s.u.kp[i]) {
                float ax1 = s.sx1[i], ay1 = s.sy1[i], ax2 = s.sx2[i], ay2 = s.sy2[i];
                float aa = (ax2 - ax1) * (ay2 - ay1);
                for (int r = i + 1 + tid; r < M; r += 1024) {
                    float bx1 = s.sx1[r], by1 = s.sy1[r], bx2 = s.sx2[r], by2 = s.sy2[r];
                    float ab = (bx2 - bx1) * (by2 - by1);
                    float ltx = fmaxf(ax1, bx1), lty = fmaxf(ay1, by1);
                    float rbx = fminf(ax2, bx2), rby = fminf(ay2, by2);
                    float ww = fmaxf(rbx - ltx, 0.0f), hh = fmaxf(rby - lty, 0.0f);
                    float inter = ww * hh;
                    float denom = ((aa + ab) - inter) + 1e-9f;
                    if ((inter / denom) > IOU_T) s.u.kp[r] = 0;
                }
            }
            __syncthreads();
        }
        if (tid == 0) {
            int c2 = 0;
            for (int r = 0; r < M && c2 < MAXDET; ++r)
                if (s.u.kp[r]) wsDst[b * MAXDET + c2++] = r;  // store RANK
            wsKept[b] = c2;
        }
    }
}

// ================= kernel 3: output write (proven) =================
__global__ __launch_bounds__(256)
void out_kernel(const float* __restrict__ score, const int* __restrict__ wsKept,
                const unsigned long long* __restrict__ wsKey,   // rank-sorted
                const int* __restrict__ wsDst, float* __restrict__ out) {
    const int b = blockIdx.x;
    const int e = blockIdx.y * 256 + threadIdx.x;
    if (e >= MAXDET * OUTC) return;
    const int row = e / OUTC, c = e - row * OUTC;
    float v = 0.0f;
    if (row < wsKept[b]) {
        unsigned long long key = wsKey[b * SLOTS + wsDst[b * MAXDET + row]];
        int n = (int)((key >> 16) & 0xFFFFULL);
        int cls = (int)((key >> 8) & 0xFFULL);
        int hw = n / 5, t5 = n - hw * 5;
        const float* base = score + (size_t)b * 425 * HWSZ + (size_t)(t5 * 85) * HWSZ + hw;
        if (c < 4) {
            float x = base[0];
            float y = base[HWSZ];
            float w = base[2 * HWSZ];
            float h = base[3 * HWSZ];
            float wh2 = w * 0.5f, hh2 = h * 0.5f;
            v = (c == 0) ? (x - wh2) : (c == 1) ? (y - hh2)
              : (c == 2) ? (x + wh2) : (y + hh2);
        } else if (c == 4) {
            v = __uint_as_float((~(unsigned int)(key >> 32)) & 0x7FFFFFFFu);
        } else if (c == 5) {
            v = (float)cls;
        } else {
            v = base[(c - 1) * HWSZ];              // raw logits
        }
    }
    out[(size_t)b * MAXDET * OUTC + e] = v;
}

// ================= last-resort fallback: round-2 single kernel (proven) =================
struct SMemFB {
    float bx1[NPRED], by1[NPRED], bx2[NPRED], by2[NPRED], area[NPRED];
    unsigned short sortedN[NPRED];
    union {
        unsigned long long vkey[NPRED];
        struct { float confR[MAXDET]; unsigned char jclsR[MAXDET]; } oi;
        unsigned char keepFB[NPRED];
    } u;
    unsigned short dstN[MAXDET];
    int validCount;
    int keptCount;
};

__device__ __forceinline__ void conf_argmax(const float* __restrict__ base, float obj,
                                            float& conf, int& bj) {
    float best = -INFINITY; int bjj = 0;
    #pragma unroll 8
    for (int k = 0; k < NCLS; ++k) {
        float v = base[(5 + k) * HWSZ] * obj;
        if (v > best) { best = v; bjj = k; }
    }
    conf = best; bj = bjj;
}

__global__ __launch_bounds__(1024)
void yolo_nms_single(const float* __restrict__ score, float* __restrict__ out) {
    __shared__ SMemFB s;
    const int b = blockIdx.x;
    const int tid = threadIdx.x;
    const float* sb = score + (size_t)b * 425 * HWSZ;
    if (tid == 0) s.validCount = 0;
    __syncthreads();
    for (int ci = tid; ci < NPRED; ci += 1024) {
        int t5 = ci / HWSZ;
        int hw = ci - t5 * HWSZ;
        int n = hw * 5 + t5;
        const float* base = sb + (size_t)(t5 * 85) * HWSZ + hw;
        float x = base[0], y = base[HWSZ], w = base[2 * HWSZ], h = base[3 * HWSZ];
        float obj = base[4 * HWSZ];
        float conf; int bj;
        conf_argmax(base, obj, conf, bj);
        bool valid = (obj > CONF_T) && (conf > CONF_T);
        float wh2 = w * 0.5f, hh2 = h * 0.5f;
        float x1 = x - wh2, y1 = y - hh2, x2 = x + wh2, y2 = y + hh2;
        float off = (float)bj * MAX_WH;
        float ox1 = x1 + off, oy1 = y1 + off, ox2 = x2 + off, oy2 = y2 + off;
        s.bx1[n] = ox1; s.by1[n] = oy1; s.bx2[n] = ox2; s.by2[n] = oy2;
        s.area[n] = (ox2 - ox1) * (oy2 - oy1);
        if (valid) {
            int slot = atomicAdd(&s.validCount, 1);
            unsigned int uu = __float_as_uint(conf);
            unsigned int desc = ~(uu | 0x80000000u);
            s.u.vkey[slot] = ((unsigned long long)desc << 32) | (unsigned int)n;
        }
    }
    __syncthreads();
    const int M = s.validCount;
    for (int vi = tid; vi < M; vi += 1024) {
        unsigned long long ki = s.u.vkey[vi];
        int rank = 0;
        for (int j = 0; j < M; ++j) rank += (s.u.vkey[j] < ki) ? 1 : 0;
        s.sortedN[rank] = (unsigned short)(ki & 0xFFFFULL);
    }
    __syncthreads();
    for (int r = tid; r < M; r += 1024) s.u.keepFB[r] = 1;
    __syncthreads();
    for (int i = 0; i < M; ++i) {
        if (s.u.keepFB[i]) {
            int ni = s.sortedN[i];
            float ax1 = s.bx1[ni], ay1 = s.by1[ni], ax2 = s.bx2[ni], ay2 = s.by2[ni];
            float aa = s.area[ni];
            for (int r = i + 1 + tid; r < M; r += 1024) {
                int nj = s.sortedN[r];
                float ltx = fmaxf(ax1, s.bx1[nj]);
                float lty = fmaxf(ay1, s.by1[nj]);
                float rbx = fminf(ax2, s.bx2[nj]);
                float rby = fminf(ay2, s.by2[nj]);
                float ww = fmaxf(rbx - ltx, 0.0f);
                float hh = fmaxf(rby - lty, 0.0f);
                float inter = ww * hh;
                float denom = ((aa + s.area[nj]) - inter) + 1e-9f;
                if ((inter / denom) > IOU_T) s.u.keepFB[r] = 0;
            }
        }
        __syncthreads();
    }
    if (tid == 0) {
        int cnt = 0;
        for (int r = 0; r < M && cnt < MAXDET; ++r)
            if (s.u.keepFB[r]) s.dstN[cnt++] = s.sortedN[r];
        s.keptCount = cnt;
    }
    __syncthreads();
    const int cnt = s.keptCount;
    if (tid < cnt) {
        int n = s.dstN[tid];
        int hw = n / 5, t5 = n - hw * 5;
        const float* base = sb + (size_t)(t5 * 85) * HWSZ + hw;
        float obj = base[4 * HWSZ];
        float conf; int bj;
        conf_argmax(base, obj, conf, bj);
        s.u.oi.confR[tid] = conf;
        s.u.oi.jclsR[tid] = (unsigned char)bj;
    }
    __syncthreads();
    float* ob = out + (size_t)b * MAXDET * OUTC;
    for (int e = tid; e < MAXDET * OUTC; e += 1024) {
        int row = e / OUTC, c = e - row * OUTC;
        float v = 0.0f;
        if (row < cnt) {
            int n = s.dstN[row];
            int hw = n / 5, t5 = n - hw * 5;
            const float* base = sb + (size_t)(t5 * 85) * HWSZ + hw;
            if (c < 4) {
                float x = base[0], y = base[HWSZ], w = base[2 * HWSZ], h = base[3 * HWSZ];
                float wh2 = w * 0.5f, hh2 = h * 0.5f;
                v = (c == 0) ? (x - wh2) : (c == 1) ? (y - hh2)
                  : (c == 2) ? (x + wh2) : (y + hh2);
            } else if (c == 4) {
                v = s.u.oi.confR[row];
            } else if (c == 5) {
                v = (float)s.u.oi.jclsR[row];
            } else {
                v = base[(c - 1) * HWSZ];
            }
        }
        ob[e] = v;
    }
}

extern "C" void kernel_launch(void* const* d_in, const int* in_sizes, int n_in,
                              void* d_out, int out_size, void* d_ws, size_t ws_size,
                              hipStream_t stream) {
    const float* score = (const float*)d_in[0];
    float* out = (float*)d_out;
    char* ws = (char*)d_ws;
    int* wsKept = (int*)ws;
    unsigned long long* wsKeyRaw = (unsigned long long*)(ws + OFF_KEYR);
    float4* wsBoxRaw = (float4*)(ws + OFF_BOXR);
    unsigned long long* wsKey = (unsigned long long*)(ws + OFF_KEY);
    int* wsDone = (int*)(ws + OFF_DONE);
    int* wsECnt = (int*)(ws + OFF_ECNT);
    unsigned int* wsEdges = (unsigned int*)(ws + OFF_EDG);
    int* wsDst = (int*)(ws + OFF_DST);

    if (ws_size >= (size_t)WS_NEED) {
        prep_kernel<<<dim3(NIMG, 12), 128, 0, stream>>>(score, wsKeyRaw, wsBoxRaw, wsDone);
        edge_scan_kernel<<<dim3(NIMG, 8), 1024, 0, stream>>>(wsKeyRaw, wsBoxRaw, wsKey,
                                                             wsECnt, wsEdges, wsDone,
                                                             wsKept, wsDst);
        out_kernel<<<dim3(NIMG, 101), 256, 0, stream>>>(score, wsKept, wsKey, wsDst, out);
    } else {
        yolo_nms_single<<<NIMG, 1024, 0, stream>>>(score, out);
    }
}

// Round 16
// 42.627 us; speedup vs baseline: 2.4428x; 2.4428x over previous
//
#include <hip/hip_runtime.h>

#define NPRED 1445
#define RAWSTR 1472    // padded per-image stride for raw arrays
#define NCLS  80
#define MAXDET 300
#define OUTC  86
#define CONF_T 0.6f
#define IOU_T  0.45f
#define MAX_WH 4096.0f
#define HWSZ  289
#define NIMG  32
#define SLOTS 768      // compacted slots per image (M mean ~396, sigma ~17)
#define MCAP  512      // edge fast-path cap (~7 sigma)
#define EPB   256      // edge capacity per (image, j-word) region
#define EWALK 2048     // 8*EPB: max edges the walk path handles

// ---- d_ws layout (bytes); total 2,022,144 (proven) ----
#define OFF_CNT  128        // int[32]   M per image (written by edge block w=0)
#define OFF_KEYR 256        // u64[32][RAWSTR]  raw keys by candidate (sentinel ~0)
#define OFF_BOXR 377088     // float4[32][RAWSTR] raw offset boxes by candidate
#define OFF_KEY  1130752    // u64[32][SLOTS]   rank-sorted keys
#define OFF_SBOX 1327360    // float4[32][SLOTS] rank-sorted boxes (fallback path)
#define OFF_ECNT 1720576    // int[32][8]       per-region edge counts
#define OFF_EDG  1721600    // u32[32][8][EPB]  edges (i<<9|j), unsorted
#define OFF_DST  1983744    // int[32][MAXDET]  RANK per kept output row
#define WS_NEED  2022144
// wsKept = int[32] at offset 0

__device__ __forceinline__ unsigned long long bcast64(unsigned long long v, int srcLane) {
    unsigned lo = (unsigned)__builtin_amdgcn_readlane((int)(unsigned)(v & 0xFFFFFFFFULL), srcLane);
    unsigned hi = (unsigned)__builtin_amdgcn_readlane((int)(unsigned)(v >> 32), srcLane);
    return ((unsigned long long)hi << 32) | lo;
}

// ================= kernel 1: per-candidate prep (deterministic slots, no atomics) =====
__global__ __launch_bounds__(128)
void prep_kernel(const float* __restrict__ score, unsigned long long* __restrict__ wsKeyRaw,
                 float4* __restrict__ wsBoxRaw) {
    const int b = blockIdx.x;
    const int ci = blockIdx.y * 128 + threadIdx.x;
    if (ci >= NPRED) return;
    const int t5 = ci / HWSZ;
    const int hw = ci - t5 * HWSZ;
    const int n = hw * 5 + t5;                     // candidate row in x[N][85]
    const float* base = score + (size_t)b * 425 * HWSZ + (size_t)(t5 * 85) * HWSZ + hw;
    float x = base[0];
    float y = base[HWSZ];
    float w = base[2 * HWSZ];
    float h = base[3 * HWSZ];
    float obj = base[4 * HWSZ];

    float best = -INFINITY; int bj = 0;
    #pragma unroll 16
    for (int k = 0; k < NCLS; ++k) {
        float v = base[(5 + k) * HWSZ] * obj;      // cls = logits * obj
        if (v > best) { best = v; bj = k; }        // strict >: first-occurrence argmax
    }

    float wh2 = w * 0.5f, hh2 = h * 0.5f;
    float x1 = x - wh2, y1 = y - hh2, x2 = x + wh2, y2 = y + hh2;
    float off = (float)bj * MAX_WH;                // exact product

    unsigned long long key = ~0ULL;                // invalid sentinel (MSB set)
    if ((obj > CONF_T) && (best > CONF_T)) {
        unsigned int u = __float_as_uint(best);    // conf > 0.6 -> positive, MSB 0
        unsigned int desc = ~(u | 0x80000000u);    // ascending u64 == descending conf
        key = ((unsigned long long)desc << 32)
            | ((unsigned long long)(unsigned)n << 16)
            | ((unsigned long long)(unsigned)bj << 8);
    }
    wsKeyRaw[b * RAWSTR + ci] = key;
    wsBoxRaw[b * RAWSTR + ci] = make_float4(x1 + off, y1 + off, x2 + off, y2 + off);
}

// ================= kernel 2: compact+sort (redundant per block) + IoU edges ===========
// grid (NIMG, 8): block (b,w) sorts locally (deterministic, identical across blocks),
// then extracts edges for j-word w with triangular i-limit. The O(M^2) ballot work
// stays spread across 256 blocks; block (b,0) persists sorted keys/boxes/M.
struct EdgeSh {
    unsigned long long keys[NPRED];                // 11560 B
    unsigned long long cke[SLOTS];                 //  6144 B
    unsigned short cidx[SLOTS];                    //  1536 B
    float sx1[SLOTS], sy1[SLOTS], sx2[SLOTS], sy2[SLOTS]; // 12288 B
    int wtot[16];
    int mTot, ecnt;
};

__global__ __launch_bounds__(1024)
void edge_kernel(const unsigned long long* __restrict__ wsKeyRaw,
                 const float4* __restrict__ wsBoxRaw,
                 int* __restrict__ wsCnt, unsigned long long* __restrict__ wsKey,
                 float4* __restrict__ wsSBox,
                 int* __restrict__ wsECnt, unsigned int* __restrict__ wsEdges) {
    __shared__ EdgeSh s;
    const int b = blockIdx.x, w = blockIdx.y, tid = threadIdx.x;
    const int lane = tid & 63, wid = tid >> 6;

    for (int i = tid; i < NPRED; i += 1024) s.keys[i] = wsKeyRaw[b * RAWSTR + i];
    if (tid == 0) s.ecnt = 0;
    __syncthreads();

    // ---- validity prefix-sum compaction (verbatim round-12 sort logic) ----
    const int i0 = tid, i1 = tid + 1024;
    const bool v0 = (s.keys[i0] >> 63) == 0ULL;               // valid keys have MSB 0
    const bool v1 = (i1 < NPRED) && ((s.keys[i1] >> 63) == 0ULL);
    int cnt = (int)v0 + (int)v1;
    int inc = cnt;
    #pragma unroll
    for (int m = 1; m < 64; m <<= 1) {
        int v = __shfl_up(inc, m, 64);
        if (lane >= m) inc += v;
    }
    if (lane == 63) s.wtot[wid] = inc;
    __syncthreads();
    int basep = 0;
    for (int w2 = 0; w2 < wid; ++w2) basep += s.wtot[w2];
    int pos = basep + inc - cnt;                              // exclusive global prefix
    if (v0 && pos < SLOTS) s.cidx[pos] = (unsigned short)i0;
    if (v1 && pos + (int)v0 < SLOTS) s.cidx[pos + (int)v0] = (unsigned short)i1;
    if (tid == 0) {
        int t = 0;
        for (int w2 = 0; w2 < 16; ++w2) t += s.wtot[w2];
        s.mTot = t;
    }
    __syncthreads();
    int M = s.mTot; if (M > SLOTS) M = SLOTS;
    if (tid < M) s.cke[tid] = s.keys[s.cidx[tid]];            // densify (M <= 768)
    __syncthreads();

    // ---- rank-count sort (identical in every block; unique keys) ----
    if (tid < M) {
        unsigned long long ki = s.cke[tid];
        int rank = 0;
        #pragma unroll 4
        for (int j2 = 0; j2 < M; ++j2) rank += (s.cke[j2] < ki) ? 1 : 0;
        float4 bx = wsBoxRaw[b * RAWSTR + s.cidx[tid]];
        s.sx1[rank] = bx.x; s.sy1[rank] = bx.y; s.sx2[rank] = bx.z; s.sy2[rank] = bx.w;
        if (w == 0) {                                         // persist once per image
            wsKey[b * SLOTS + rank] = ki;
            wsSBox[b * SLOTS + rank] = bx;
        }
    }
    if (w == 0 && tid == 0) wsCnt[b] = M;
    __syncthreads();

    if (M > MCAP) { if (tid == 0) wsECnt[b * 8 + w] = 0x7FFFFFFF; return; }

    // ---- edge extraction for j-word w, triangular i-limit ----
    unsigned int* reg = wsEdges + (size_t)(b * 8 + w) * EPB;
    const int j = (w << 6) + lane;
    float jx1 = 0.f, jy1 = 0.f, jx2 = 0.f, jy2 = 0.f, ab = 0.f;
    const bool jok = (j < M);
    if (jok) {
        jx1 = s.sx1[j]; jy1 = s.sy1[j]; jx2 = s.sx2[j]; jy2 = s.sy2[j];
        ab = (jx2 - jx1) * (jy2 - jy1);
    }
    int ilim = (w + 1) << 6; if (ilim > M) ilim = M;          // only i < max j matter
    for (int i = wid; i < ilim; i += 16) {
        float ax1 = s.sx1[i], ay1 = s.sy1[i], ax2 = s.sx2[i], ay2 = s.sy2[i];
        float aa = (ax2 - ax1) * (ay2 - ay1);
        bool sup = false;
        if (jok && j > i) {
            float ltx = fmaxf(ax1, jx1), lty = fmaxf(ay1, jy1);
            float rbx = fminf(ax2, jx2), rby = fminf(ay2, jy2);
            float ww = fmaxf(rbx - ltx, 0.0f), hh = fmaxf(rby - lty, 0.0f);
            float inter = ww * hh;
            float denom = ((aa + ab) - inter) + 1e-9f;        // left-to-right, exact div
            sup = (inter / denom) > IOU_T;
        }
        unsigned long long mask = __ballot(sup);
        if (lane == 0 && mask) {
            int pc = __popcll(mask);
            int eb = atomicAdd(&s.ecnt, pc);                  // LDS atomic, block-local
            int k = 0;
            while (mask) {
                int bit = __ffsll((long long)mask) - 1;
                mask &= mask - 1;
                int p = eb + k;
                if (p < EPB) reg[p] = ((unsigned)i << 9) | (unsigned)((w << 6) + bit);
                ++k;
            }
        }
    }
    __syncthreads();
    if (tid == 0) wsECnt[b * 8 + w] = s.ecnt;                 // > EPB signals overflow
}

// ================= kernel 3: edge sort + single-wave greedy walk (proven) ====
struct ScanSh {
    union {
        struct {
            float x1[SLOTS], y1[SLOTS], x2[SLOTS], y2[SLOTS];
            unsigned char kp[SLOTS];
        } fb;                                             // fallback arrays (~13 KB)
        struct { unsigned int eraw[EWALK]; unsigned int esrt[EWALK]; } e; // 16 KB
    } u;
    int ec[8];
    int eoff[9];
    int over;
};

__global__ __launch_bounds__(256)
void scan_kernel(const int* __restrict__ wsCnt, const int* __restrict__ wsECnt,
                 const unsigned int* __restrict__ wsEdges, const float4* __restrict__ wsSBox,
                 int* __restrict__ wsKept, int* __restrict__ wsDst) {
    __shared__ ScanSh sh;
    const int b = blockIdx.x, tid = threadIdx.x, lane = tid & 63;
    int M = wsCnt[b]; if (M > SLOTS) M = SLOTS;
    if (tid < 8) sh.ec[tid] = wsECnt[b * 8 + tid];
    if (tid == 0) sh.over = 0;
    __syncthreads();
    if (tid == 0) {
        int o = 0;
        for (int w = 0; w < 8; ++w) {
            sh.eoff[w] = o;
            int c = sh.ec[w];
            if (c > EPB) { sh.over = 1; c = EPB; }
            o += c;
        }
        sh.eoff[8] = o;
    }
    __syncthreads();
    const bool fast = (M <= MCAP) && (sh.over == 0);
    const int Etot = sh.eoff[8];

    if (fast) {
        // ---- gather edges from 8 regions into LDS ----
        for (int w = 0; w < 8; ++w) {
            int c = sh.ec[w]; if (c > EPB) c = EPB;
            const unsigned int* reg = wsEdges + (size_t)(b * 8 + w) * EPB;
            for (int e2 = tid; e2 < c; e2 += 256) sh.u.e.eraw[sh.eoff[w] + e2] = reg[e2];
        }
        __syncthreads();
        // ---- rank-count sort (unique (i<<9|j) values) ----
        for (int e2 = tid; e2 < Etot; e2 += 256) {
            unsigned int ke = sh.u.e.eraw[e2];
            int rank = 0;
            for (int j2 = 0; j2 < Etot; ++j2) rank += (sh.u.e.eraw[j2] < ke) ? 1 : 0;
            sh.u.e.esrt[rank] = ke;
        }
        __syncthreads();
        if (tid >= 64) return;                      // single wave below
        // ---- edge walk: lane l owns keep word l ----
        unsigned long long Kw = 0ULL;
        { int rem = M - (lane << 6);
          if (rem >= 64) Kw = ~0ULL; else if (rem > 0) Kw = (~0ULL) >> (64 - rem); }
        unsigned int A[8], B[8];
#define LOADE(buf, bs) { _Pragma("unroll") for (int k = 0; k < 8; ++k) { \
        int e2 = (bs) + k; buf[k] = (e2 < Etot) ? sh.u.e.esrt[e2] : 0xFFFFFFFFu; } }
#define PROCE(buf) { _Pragma("unroll") for (int k = 0; k < 8; ++k) { \
        unsigned int ek = buf[k]; \
        if (ek != 0xFFFFFFFFu) { \
            int ei = (int)(ek >> 9), ej = (int)(ek & 511u); \
            unsigned long long kwi = bcast64(Kw, ei >> 6); \
            if ((kwi >> (ei & 63)) & 1ULL) { \
                if (lane == (ej >> 6)) Kw &= ~(1ULL << (ej & 63)); \
            } } } }
        LOADE(A, 0)
        for (int e = 0; e < Etot; e += 16) {
            LOADE(B, e + 8)
            PROCE(A)
            LOADE(A, e + 16)
            PROCE(B)
        }
#undef LOADE
#undef PROCE
        // ---- compaction: lane-parallel popcount prefix ----
        int myc = __popcll(Kw);
        int incc = myc;
        #pragma unroll
        for (int m = 1; m < 64; m <<= 1) {
            int v = __shfl_up(incc, m, 64);
            if (lane >= m) incc += v;
        }
        int tot = __shfl(incc, 63, 64);
        if (lane == 0) wsKept[b] = (tot < MAXDET) ? tot : MAXDET;
        int r = incc - myc;                         // exclusive prefix
        unsigned long long kw = Kw;
        while (kw) {
            int i = __ffsll((long long)kw) - 1;
            kw &= kw - 1;
            if (r < MAXDET) wsDst[b * MAXDET + r] = (lane << 6) + i;  // RANK
            ++r;
        }
    } else {
        // ---- fallback (M > MCAP or edge overflow, ~0 prob): barrier-serial greedy ----
        for (int r = tid; r < M; r += 256) {
            float4 v = wsSBox[b * SLOTS + r];
            sh.u.fb.x1[r] = v.x; sh.u.fb.y1[r] = v.y;
            sh.u.fb.x2[r] = v.z; sh.u.fb.y2[r] = v.w; sh.u.fb.kp[r] = 1;
        }
        __syncthreads();
        for (int i = 0; i < M; ++i) {
            if (sh.u.fb.kp[i]) {
                float ax1 = sh.u.fb.x1[i], ay1 = sh.u.fb.y1[i];
                float ax2 = sh.u.fb.x2[i], ay2 = sh.u.fb.y2[i];
                float aa = (ax2 - ax1) * (ay2 - ay1);
                for (int r = i + 1 + tid; r < M; r += 256) {
                    float bx1 = sh.u.fb.x1[r], by1 = sh.u.fb.y1[r];
                    float bx2 = sh.u.fb.x2[r], by2 = sh.u.fb.y2[r];
                    float ab = (bx2 - bx1) * (by2 - by1);
                    float ltx = fmaxf(ax1, bx1), lty = fmaxf(ay1, by1);
                    float rbx = fminf(ax2, bx2), rby = fminf(ay2, by2);
                    float ww = fmaxf(rbx - ltx, 0.0f), hh = fmaxf(rby - lty, 0.0f);
                    float inter = ww * hh;
                    float denom = ((aa + ab) - inter) + 1e-9f;
                    if ((inter / denom) > IOU_T) sh.u.fb.kp[r] = 0;
                }
            }
            __syncthreads();
        }
        if (tid == 0) {
            int c2 = 0;
            for (int r = 0; r < M && c2 < MAXDET; ++r)
                if (sh.u.fb.kp[r]) wsDst[b * MAXDET + c2++] = r;    // store RANK
            wsKept[b] = c2;
        }
    }
}

// ================= kernel 4: output write (proven) =================
__global__ __launch_bounds__(256)
void out_kernel(const float* __restrict__ score, const int* __restrict__ wsKept,
                const unsigned long long* __restrict__ wsKey,   // rank-sorted
                const int* __restrict__ wsDst, float* __restrict__ out) {
    const int b = blockIdx.x;
    const int e = blockIdx.y * 256 + threadIdx.x;
    if (e >= MAXDET * OUTC) return;
    const int row = e / OUTC, c = e - row * OUTC;
    float v = 0.0f;
    if (row < wsKept[b]) {
        unsigned long long key = wsKey[b * SLOTS + wsDst[b * MAXDET + row]];
        int n = (int)((key >> 16) & 0xFFFFULL);
        int cls = (int)((key >> 8) & 0xFFULL);
        int hw = n / 5, t5 = n - hw * 5;
        const float* base = score + (size_t)b * 425 * HWSZ + (size_t)(t5 * 85) * HWSZ + hw;
        if (c < 4) {
            float x = base[0];
            float y = base[HWSZ];
            float w = base[2 * HWSZ];
            float h = base[3 * HWSZ];
            float wh2 = w * 0.5f, hh2 = h * 0.5f;
            v = (c == 0) ? (x - wh2) : (c == 1) ? (y - hh2)
              : (c == 2) ? (x + wh2) : (y + hh2);
        } else if (c == 4) {
            v = __uint_as_float((~(unsigned int)(key >> 32)) & 0x7FFFFFFFu);
        } else if (c == 5) {
            v = (float)cls;
        } else {
            v = base[(c - 1) * HWSZ];              // raw logits
        }
    }
    out[(size_t)b * MAXDET * OUTC + e] = v;
}

// ================= last-resort fallback: round-2 single kernel (proven) =================
struct SMemFB {
    float bx1[NPRED], by1[NPRED], bx2[NPRED], by2[NPRED], area[NPRED];
    unsigned short sortedN[NPRED];
    union {
        unsigned long long vkey[NPRED];
        struct { float confR[MAXDET]; unsigned char jclsR[MAXDET]; } oi;
        unsigned char keepFB[NPRED];
    } u;
    unsigned short dstN[MAXDET];
    int validCount;
    int keptCount;
};

__device__ __forceinline__ void conf_argmax(const float* __restrict__ base, float obj,
                                            float& conf, int& bj) {
    float best = -INFINITY; int bjj = 0;
    #pragma unroll 8
    for (int k = 0; k < NCLS; ++k) {
        float v = base[(5 + k) * HWSZ] * obj;
        if (v > best) { best = v; bjj = k; }
    }
    conf = best; bj = bjj;
}

__global__ __launch_bounds__(1024)
void yolo_nms_single(const float* __restrict__ score, float* __restrict__ out) {
    __shared__ SMemFB s;
    const int b = blockIdx.x;
    const int tid = threadIdx.x;
    const float* sb = score + (size_t)b * 425 * HWSZ;
    if (tid == 0) s.validCount = 0;
    __syncthreads();
    for (int ci = tid; ci < NPRED; ci += 1024) {
        int t5 = ci / HWSZ;
        int hw = ci - t5 * HWSZ;
        int n = hw * 5 + t5;
        const float* base = sb + (size_t)(t5 * 85) * HWSZ + hw;
        float x = base[0], y = base[HWSZ], w = base[2 * HWSZ], h = base[3 * HWSZ];
        float obj = base[4 * HWSZ];
        float conf; int bj;
        conf_argmax(base, obj, conf, bj);
        bool valid = (obj > CONF_T) && (conf > CONF_T);
        float wh2 = w * 0.5f, hh2 = h * 0.5f;
        float x1 = x - wh2, y1 = y - hh2, x2 = x + wh2, y2 = y + hh2;
        float off = (float)bj * MAX_WH;
        float ox1 = x1 + off, oy1 = y1 + off, ox2 = x2 + off, oy2 = y2 + off;
        s.bx1[n] = ox1; s.by1[n] = oy1; s.bx2[n] = ox2; s.by2[n] = oy2;
        s.area[n] = (ox2 - ox1) * (oy2 - oy1);
        if (valid) {
            int slot = atomicAdd(&s.validCount, 1);
            unsigned int uu = __float_as_uint(conf);
            unsigned int desc = ~(uu | 0x80000000u);
            s.u.vkey[slot] = ((unsigned long long)desc << 32) | (unsigned int)n;
        }
    }
    __syncthreads();
    const int M = s.validCount;
    for (int vi = tid; vi < M; vi += 1024) {
        unsigned long long ki = s.u.vkey[vi];
        int rank = 0;
        for (int j = 0; j < M; ++j) rank += (s.u.vkey[j] < ki) ? 1 : 0;
        s.sortedN[rank] = (unsigned short)(ki & 0xFFFFULL);
    }
    __syncthreads();
    for (int r = tid; r < M; r += 1024) s.u.keepFB[r] = 1;
    __syncthreads();
    for (int i = 0; i < M; ++i) {
        if (s.u.keepFB[i]) {
            int ni = s.sortedN[i];
            float ax1 = s.bx1[ni], ay1 = s.by1[ni], ax2 = s.bx2[ni], ay2 = s.by2[ni];
            float aa = s.area[ni];
            for (int r = i + 1 + tid; r < M; r += 1024) {
                int nj = s.sortedN[r];
                float ltx = fmaxf(ax1, s.bx1[nj]);
                float lty = fmaxf(ay1, s.by1[nj]);
                float rbx = fminf(ax2, s.bx2[nj]);
                float rby = fminf(ay2, s.by2[nj]);
                float ww = fmaxf(rbx - ltx, 0.0f);
                float hh = fmaxf(rby - lty, 0.0f);
                float inter = ww * hh;
                float denom = ((aa + s.area[nj]) - inter) + 1e-9f;
                if ((inter / denom) > IOU_T) s.u.keepFB[r] = 0;
            }
        }
        __syncthreads();
    }
    if (tid == 0) {
        int cnt = 0;
        for (int r = 0; r < M && cnt < MAXDET; ++r)
            if (s.u.keepFB[r]) s.dstN[cnt++] = s.sortedN[r];
        s.keptCount = cnt;
    }
    __syncthreads();
    const int cnt = s.keptCount;
    if (tid < cnt) {
        int n = s.dstN[tid];
        int hw = n / 5, t5 = n - hw * 5;
        const float* base = sb + (size_t)(t5 * 85) * HWSZ + hw;
        float obj = base[4 * HWSZ];
        float conf; int bj;
        conf_argmax(base, obj, conf, bj);
        s.u.oi.confR[tid] = conf;
        s.u.oi.jclsR[tid] = (unsigned char)bj;
    }
    __syncthreads();
    float* ob = out + (size_t)b * MAXDET * OUTC;
    for (int e = tid; e < MAXDET * OUTC; e += 1024) {
        int row = e / OUTC, c = e - row * OUTC;
        float v = 0.0f;
        if (row < cnt) {
            int n = s.dstN[row];
            int hw = n / 5, t5 = n - hw * 5;
            const float* base = sb + (size_t)(t5 * 85) * HWSZ + hw;
            if (c < 4) {
                float x = base[0], y = base[HWSZ], w = base[2 * HWSZ], h = base[3 * HWSZ];
                float wh2 = w * 0.5f, hh2 = h * 0.5f;
                v = (c == 0) ? (x - wh2) : (c == 1) ? (y - hh2)
                  : (c == 2) ? (x + wh2) : (y + hh2);
            } else if (c == 4) {
                v = s.u.oi.confR[row];
            } else if (c == 5) {
                v = (float)s.u.oi.jclsR[row];
            } else {
                v = base[(c - 1) * HWSZ];
            }
        }
        ob[e] = v;
    }
}

extern "C" void kernel_launch(void* const* d_in, const int* in_sizes, int n_in,
                              void* d_out, int out_size, void* d_ws, size_t ws_size,
                              hipStream_t stream) {
    const float* score = (const float*)d_in[0];
    float* out = (float*)d_out;
    char* ws = (char*)d_ws;
    int* wsKept = (int*)ws;
    int* wsCnt  = (int*)(ws + OFF_CNT);
    unsigned long long* wsKeyRaw = (unsigned long long*)(ws + OFF_KEYR);
    float4* wsBoxRaw = (float4*)(ws + OFF_BOXR);
    unsigned long long* wsKey = (unsigned long long*)(ws + OFF_KEY);
    float4* wsSBox = (float4*)(ws + OFF_SBOX);
    int* wsECnt = (int*)(ws + OFF_ECNT);
    unsigned int* wsEdges = (unsigned int*)(ws + OFF_EDG);
    int* wsDst = (int*)(ws + OFF_DST);

    if (ws_size >= (size_t)WS_NEED) {
        prep_kernel<<<dim3(NIMG, 12), 128, 0, stream>>>(score, wsKeyRaw, wsBoxRaw);
        edge_kernel<<<dim3(NIMG, 8), 1024, 0, stream>>>(wsKeyRaw, wsBoxRaw, wsCnt,
                                                        wsKey, wsSBox, wsECnt, wsEdges);
        scan_kernel<<<NIMG, 256, 0, stream>>>(wsCnt, wsECnt, wsEdges, wsSBox, wsKept, wsDst);
        out_kernel<<<dim3(NIMG, 101), 256, 0, stream>>>(score, wsKept, wsKey, wsDst, out);
    } else {
        yolo_nms_single<<<NIMG, 1024, 0, stream>>>(score, out);
    }
}